// Round 4
// baseline (220.782 us; speedup 1.0000x reference)
//
#include <hip/hip_runtime.h>
#include <cstdint>

typedef unsigned long long u64;
typedef unsigned int u32;

#define CLS_T    0.05f
#define TOPK     300
#define NWORDS   5          // ceil(300/64)
#define HBINS    2560
#define KEY_BASE 0x3D000000u
#define NSEG     8
#define SEGCAP   512
#define CCAP     2048       // class_nms candidate cap
#define TTA      128        // anchors per transpose tile

// score -> coarse bin (0 = below threshold)
__device__ inline unsigned short score_bin(float s) {
    if (!(s > CLS_T)) return 0;
    u32 k = __float_as_uint(s) - KEY_BASE;
    u32 b = k >> 14;
    if (b > (HBINS - 1)) b = HBINS - 1;
    return (unsigned short)b;
}
__device__ inline u32 bin_of_bits(u32 bits) {
    u32 b = (bits - KEY_BASE) >> 14;
    if (b > (HBINS - 1)) b = HBINS - 1;
    return b;
}

// ---------------- decode boxes (+clip) + zero akey ----------------
__global__ void decode_kernel(const float* __restrict__ anc,
                              const float* __restrict__ reg,
                              const int* __restrict__ ph,
                              const int* __restrict__ pw,
                              float* __restrict__ boxes,
                              u64* __restrict__ akey, int A)
{
    int a = blockIdx.x * blockDim.x + threadIdx.x;
    if (a >= A) return;
    akey[a] = 0;
    float x1 = anc[a*4+0], y1 = anc[a*4+1], x2 = anc[a*4+2], y2 = anc[a*4+3];
    float w = x2 - x1, h = y2 - y1;
    float cx = x1 + 0.5f*w, cy = y1 + 0.5f*h;
    float r0 = reg[a*4+0]*0.1f, r1 = reg[a*4+1]*0.1f;
    float r2 = reg[a*4+2]*0.2f, r3 = reg[a*4+3]*0.2f;
    float pcx = cx + r0*w, pcy = cy + r1*h;
    float pw_ = expf(r2)*w, ph_ = expf(r3)*h;
    float W = (float)(*pw), H = (float)(*ph);
    boxes[a*4+0] = fmaxf(pcx - 0.5f*pw_, 0.0f);
    boxes[a*4+1] = fmaxf(pcy - 0.5f*ph_, 0.0f);
    boxes[a*4+2] = fminf(pcx + 0.5f*pw_, W);
    boxes[a*4+3] = fminf(pcy + 0.5f*ph_, H);
}

// ---------------- transpose cls[A][80] -> bin16[80][A] ----------------
__global__ __launch_bounds__(256) void transpose_bin_kernel(
    const float* __restrict__ in, unsigned short* __restrict__ out, int A)
{
    const int C = 80;
    __shared__ unsigned short tile[TTA][81];
    int a0 = blockIdx.x * TTA;
    int rows = A - a0; if (rows > TTA) rows = TTA;

    if (rows == TTA) {
        const float4* in4 = (const float4*)(in + (size_t)a0 * C);
        for (int w = threadIdx.x; w < TTA * C / 4; w += 256) {
            float4 v = in4[w];
            int l = w * 4; int r = l / C; int cc = l - r * C;
            tile[r][cc+0] = score_bin(v.x);
            tile[r][cc+1] = score_bin(v.y);
            tile[r][cc+2] = score_bin(v.z);
            tile[r][cc+3] = score_bin(v.w);
        }
        __syncthreads();
        for (int m = threadIdx.x; m < C * (TTA/2); m += 256) {
            int cc = m >> 6;
            int r2 = (m & (TTA/2 - 1)) << 1;
            u32 wv = (u32)tile[r2][cc] | ((u32)tile[r2+1][cc] << 16);
            *(u32*)(out + (size_t)cc * A + a0 + r2) = wv;
        }
    } else {
        for (int l = threadIdx.x; l < rows * C; l += 256) {
            int r = l / C; int cc = l - r * C;
            tile[r][cc] = score_bin(in[(size_t)(a0 + r) * C + cc]);
        }
        __syncthreads();
        for (int m = threadIdx.x; m < C * rows; m += 256) {
            int cc = m / rows; int r = m - cc * rows;
            out[(size_t)cc * A + a0 + r] = tile[r][cc];
        }
    }
}

// ---------------- per-(class,segment) selection + global hist merge ----------------
__global__ __launch_bounds__(256) void seg_select_kernel(
    const unsigned short* __restrict__ clsT16,
    const float* __restrict__ cls,     // [A][C] exact scores for gather
    u32* __restrict__ ghist,           // [C][HBINS], pre-zeroed
    u64* __restrict__ segcand, u32* __restrict__ segcnt,
    int A, int C, int segsz)
{
    const int blk = blockIdx.x;
    const int c = blk >> 3, seg = blk & 7;
    const int tid = threadIdx.x;
    int a0 = seg * segsz;
    int a1 = a0 + segsz; if (a1 > A) a1 = A;

    __shared__ u32 hist[HBINS];
    __shared__ u32 psum[256];
    __shared__ u32 s_sel, s_cnt;

    if (a0 >= A) { if (tid == 0) segcnt[blk] = 0; return; }

    for (int i = tid; i < HBINS; i += 256) hist[i] = 0;
    if (tid == 0) { s_sel = 0; s_cnt = 0; }
    __syncthreads();

    const unsigned short* row = clsT16 + (size_t)c * A;
    const int n = a1 - a0;
    const int n8 = n >> 3;
    const uint4* p4 = (const uint4*)(row + a0);
    for (int i = tid; i < n8; i += 256) {
        uint4 v = p4[i];
        u32 ws[4] = {v.x, v.y, v.z, v.w};
        #pragma unroll
        for (int q = 0; q < 4; ++q) {
            u32 e0 = ws[q] & 0xFFFFu, e1 = ws[q] >> 16;
            if (e0) atomicAdd(&hist[e0], 1u);
            if (e1) atomicAdd(&hist[e1], 1u);
        }
    }
    for (int a = a0 + (n8 << 3) + tid; a < a1; a += 256) {
        u32 e = row[a];
        if (e) atomicAdd(&hist[e], 1u);
    }
    __syncthreads();

    // merge into global per-class histogram
    for (int i = tid; i < HBINS; i += 256) {
        u32 h = hist[i];
        if (h) atomicAdd(&ghist[(size_t)c * HBINS + i], h);
    }

    // parallel suffix-scan: largest bin with segment-suffix >= 300
    {
        int lo = tid * 10, hi2 = lo + 10;
        u32 s = 0;
        for (int d = lo; d < hi2; ++d) s += hist[d];
        psum[tid] = s;
        __syncthreads();
        for (int d = 1; d < 256; d <<= 1) {
            u32 v = (tid + d < 256) ? psum[tid + d] : 0;
            __syncthreads();
            psum[tid] += v;
            __syncthreads();
        }
        u32 base = (tid < 255) ? psum[tid + 1] : 0;
        if (base < TOPK && psum[tid] >= TOPK) {
            u32 run = base;
            for (int d = hi2 - 1; d >= lo; --d) {
                run += hist[d];
                if (run >= TOPK) { s_sel = (u32)d; break; }
            }
        }
        __syncthreads();
    }
    u32 sel = s_sel < 1 ? 1 : s_sel;

    // collect: rescan segment (L2-resident), gather exact bits
    u64* outc = segcand + (size_t)blk * SEGCAP;
    for (int a = a0 + tid; a < a1; a += 256) {
        u32 e = row[a];
        if (e >= sel) {
            u32 bits = __float_as_uint(cls[(size_t)a * C + c]);
            u32 p = atomicAdd(&s_cnt, 1u);
            if (p < SEGCAP) outc[p] = ((u64)bits << 32) | (u32)(~(u32)a);
        }
    }
    __syncthreads();
    if (tid == 0) segcnt[blk] = s_cnt < SEGCAP ? s_cnt : SEGCAP;
}

// ---------------- per-class: threshold from ghist, filtered load, sort, NMS ----------------
__global__ __launch_bounds__(512) void class_nms_kernel(
    const u32* __restrict__ ghist,
    const u64* __restrict__ segcand, const u32* __restrict__ segcnt,
    const float* __restrict__ boxes, u64* __restrict__ akey, int A, int C)
{
    const int c = blockIdx.x;
    const int tid = threadIdx.x;
    const int lane = tid & 63;

    __shared__ u64 cand[CCAP];
    __shared__ u32 psum[512];
    __shared__ u32 s_sel, s_cnt;
    __shared__ float bx1[TOPK], by1[TOPK], bx2[TOPK], by2[TOPK], bar[TOPK];
    __shared__ u64 iomask[TOPK][NWORDS];
    __shared__ u64 keepm[NWORDS];

    if (tid == 0) { s_sel = 0; s_cnt = 0; }
    __syncthreads();

    // ---- threshold: suffix scan over global class histogram ----
    {
        const u32* gh = ghist + (size_t)c * HBINS;
        int lo = tid * 5, hi2 = lo + 5;
        u32 h[5];
        u32 s = 0;
        #pragma unroll
        for (int q = 0; q < 5; ++q) { h[q] = gh[lo + q]; s += h[q]; }
        psum[tid] = s;
        __syncthreads();
        for (int d = 1; d < 512; d <<= 1) {
            u32 v = (tid + d < 512) ? psum[tid + d] : 0;
            __syncthreads();
            psum[tid] += v;
            __syncthreads();
        }
        u32 base = (tid < 511) ? psum[tid + 1] : 0;
        if (base < TOPK && psum[tid] >= TOPK) {
            u32 run = base;
            for (int q = 4; q >= 0; --q) {
                run += h[q];
                if (run >= TOPK) { s_sel = (u32)(lo + q); break; }
            }
        }
        __syncthreads();
    }
    const u32 thr = s_sel < 1 ? 1 : s_sel;

    // ---- filtered load + wave-aggregated compaction ----
    for (int s2 = 0; s2 < NSEG; ++s2) {
        int cnt_s = (int)segcnt[c * NSEG + s2];
        const u64* src = segcand + (size_t)(c * NSEG + s2) * SEGCAP;
        for (int i = tid; i < cnt_s; i += 512) {
            u64 e = src[i];
            bool take = bin_of_bits((u32)(e >> 32)) >= thr;
            u64 m = __ballot(take);
            int nW = __popcll(m);
            if (nW) {
                int ldr = __ffsll((unsigned long long)m) - 1;
                u32 base = 0;
                if (lane == ldr) base = atomicAdd(&s_cnt, (u32)nW);
                base = __shfl(base, ldr);
                if (take) {
                    u32 p = base + (u32)__popcll(m & ((1ull << lane) - 1ull));
                    if (p < CCAP) cand[p] = e;
                }
            }
        }
    }
    __syncthreads();
    const u32 cnt = s_cnt < CCAP ? s_cnt : CCAP;

    // ---- bitonic sort descending (pow2 N >= cnt, min 512) ----
    u32 N = 512; while (N < cnt) N <<= 1;
    for (u32 i = cnt + tid; i < N; i += 512) cand[i] = 0;
    __syncthreads();
    for (u32 kk = 2; kk <= N; kk <<= 1) {
        for (u32 j = kk >> 1; j > 0; j >>= 1) {
            for (u32 i = tid; i < N; i += 512) {
                u32 l = i ^ j;
                if (l > i) {
                    u64 av = cand[i], bv = cand[l];
                    bool up = ((i & kk) == 0);
                    if ((up && av < bv) || (!up && av > bv)) { cand[i] = bv; cand[l] = av; }
                }
            }
            __syncthreads();
        }
    }
    const int T = (int)(cnt < TOPK ? cnt : TOPK);

    // ---- candidate boxes ----
    for (int i = tid; i < T; i += 512) {
        u32 a = ~(u32)(cand[i] & 0xFFFFFFFFull);
        float x1 = boxes[(size_t)a*4+0], y1 = boxes[(size_t)a*4+1];
        float x2 = boxes[(size_t)a*4+2], y2 = boxes[(size_t)a*4+3];
        bx1[i] = x1; by1[i] = y1; bx2[i] = x2; by2[i] = y2;
        bar[i] = fmaxf(x2 - x1, 0.0f) * fmaxf(y2 - y1, 0.0f);
    }
    __syncthreads();

    // ---- pairwise IoU masks ----
    for (int i = tid; i < T; i += 512) {
        u64 m[NWORDS] = {0,0,0,0,0};
        float x1 = bx1[i], y1 = by1[i], x2 = bx2[i], y2 = by2[i], ai = bar[i];
        for (int j = i + 1; j < T; ++j) {
            float iw = fmaxf(fminf(x2, bx2[j]) - fmaxf(x1, bx1[j]), 0.0f);
            float ih = fmaxf(fminf(y2, by2[j]) - fmaxf(y1, by1[j]), 0.0f);
            float inter = iw * ih;
            float uni = ((ai + bar[j]) - inter) + 1e-8f;
            if (inter / uni > 0.5f) m[j >> 6] |= 1ull << (j & 63);
        }
        for (int k2 = 0; k2 < NWORDS; ++k2) iomask[i][k2] = m[k2];
    }
    __syncthreads();

    // ---- greedy suppression, leader-skip ----
    if (tid == 0) {
        u64 sup[NWORDS] = {0,0,0,0,0};
        u64 kp [NWORDS] = {0,0,0,0,0};
        int i = 0;
        while (i < T) {
            kp[i >> 6] |= 1ull << (i & 63);
            #pragma unroll
            for (int k2 = 0; k2 < NWORDS; ++k2) sup[k2] |= iomask[i][k2];
            sup[i >> 6] |= 1ull << (i & 63);
            int ni = T;
            for (int k2 = i >> 6; k2 < NWORDS; ++k2) {
                u64 m = ~sup[k2];
                if (k2 == (i >> 6)) m &= ~((2ull << (i & 63)) - 1ull);
                if (m) { ni = (k2 << 6) + __ffsll((unsigned long long)m) - 1; break; }
            }
            i = ni;
        }
        for (int k2 = 0; k2 < NWORDS; ++k2) keepm[k2] = kp[k2];
    }
    __syncthreads();

    // ---- scatter kept: per-anchor max via u64 atomicMax ----
    for (int i = tid; i < T; i += 512) {
        if ((keepm[i >> 6] >> (i & 63)) & 1ull) {
            u64 key = cand[i];
            u32 a = ~(u32)(key & 0xFFFFFFFFull);
            u32 sbits = (u32)(key >> 32);
            u64 outk = ((u64)sbits << 32) | (u32)(255 - c);
            atomicMax(&akey[a], outk);
        }
    }
}

// ---------------- finalize ----------------
__global__ void finalize_kernel(const u64* __restrict__ akey,
                                float* __restrict__ out, int A)
{
    int a = blockIdx.x * blockDim.x + threadIdx.x;
    if (a >= A) return;
    float* scores = out;
    float* labels = out + A;
    float* boxes  = out + (size_t)2 * A;
    u64 k = akey[a];
    if (k) {
        scores[a] = __uint_as_float((u32)(k >> 32));
        labels[a] = (float)(int)(255u - (u32)(k & 0xFFFFFFFFull));
    } else {
        scores[a] = 0.0f;
        labels[a] = -1.0f;
        boxes[(size_t)a*4+0] = 0.0f;
        boxes[(size_t)a*4+1] = 0.0f;
        boxes[(size_t)a*4+2] = 0.0f;
        boxes[(size_t)a*4+3] = 0.0f;
    }
}

// ---------------- fallback: round-1 proven kernel ----------------
#define FB_CAP 1024
__global__ __launch_bounds__(256) void fb_topk_nms_kernel(
    const float* __restrict__ cls,
    const float* __restrict__ boxes,
    u64* __restrict__ akey,
    int A, int C)
{
    const int c   = blockIdx.x;
    const int tid = threadIdx.x;

    __shared__ u32 hist[HBINS];
    __shared__ u64 cand[FB_CAP];
    __shared__ float bx1[TOPK], by1[TOPK], bx2[TOPK], by2[TOPK], bar[TOPK];
    __shared__ u64 iomask[TOPK][NWORDS];
    __shared__ u64 keepm[NWORDS];
    __shared__ u32 s_sel1, s_sel2, s_rem, s_cnt;

    for (int i = tid; i < HBINS; i += 256) hist[i] = 0;
    __syncthreads();
    for (int a = tid; a < A; a += 256) {
        float s = cls[(size_t)a * C + c];
        if (s > CLS_T) {
            u32 k = __float_as_uint(s) - KEY_BASE;
            u32 b = k >> 14; if (b >= HBINS) b = HBINS - 1;
            atomicAdd(&hist[b], 1u);
        }
    }
    __syncthreads();
    if (tid == 0) {
        u32 cum = 0; int sel = 0;
        for (int d = HBINS - 1; d >= 0; --d) {
            u32 nc = cum + hist[d];
            if (nc >= TOPK) { sel = d; break; }
            cum = nc;
        }
        s_sel1 = (u32)sel; s_rem = TOPK - cum;
    }
    __syncthreads();
    const u32 sel1 = s_sel1;

    for (int i = tid; i < 256; i += 256) hist[i] = 0;
    __syncthreads();
    for (int a = tid; a < A; a += 256) {
        float s = cls[(size_t)a * C + c];
        if (s > CLS_T) {
            u32 k = __float_as_uint(s) - KEY_BASE;
            u32 b = k >> 14; if (b >= HBINS) b = HBINS - 1;
            if (b == sel1) atomicAdd(&hist[(k >> 6) & 0xFF], 1u);
        }
    }
    __syncthreads();
    if (tid == 0) {
        u32 rem = s_rem, cum = 0; int sel = 0;
        for (int d = 255; d >= 0; --d) {
            u32 nc = cum + hist[d];
            if (nc >= rem) { sel = d; break; }
            cum = nc;
        }
        s_sel2 = (u32)sel; s_cnt = 0;
    }
    __syncthreads();
    const u32 thresh = (sel1 << 14) | (s_sel2 << 6);

    for (int a = tid; a < A; a += 256) {
        float s = cls[(size_t)a * C + c];
        if (s > CLS_T) {
            u32 bits = __float_as_uint(s);
            u32 k = bits - KEY_BASE;
            if (k >= thresh) {
                u32 pos = atomicAdd(&s_cnt, 1u);
                if (pos < FB_CAP) cand[pos] = ((u64)bits << 32) | (u32)(~(u32)a);
            }
        }
    }
    __syncthreads();
    const u32 total = s_cnt < FB_CAP ? s_cnt : FB_CAP;
    for (int i = tid; i < FB_CAP; i += 256)
        if (i >= (int)total) cand[i] = 0;
    __syncthreads();

    for (u32 kk = 2; kk <= FB_CAP; kk <<= 1) {
        for (u32 j = kk >> 1; j > 0; j >>= 1) {
            for (u32 i = tid; i < FB_CAP; i += 256) {
                u32 l = i ^ j;
                if (l > i) {
                    u64 av = cand[i], bv = cand[l];
                    bool up = ((i & kk) == 0);
                    if ((up && av < bv) || (!up && av > bv)) { cand[i] = bv; cand[l] = av; }
                }
            }
            __syncthreads();
        }
    }
    const int T = (int)(total < TOPK ? total : TOPK);

    for (int i = tid; i < T; i += 256) {
        u32 a = ~(u32)(cand[i] & 0xFFFFFFFFull);
        float x1 = boxes[(size_t)a*4+0], y1 = boxes[(size_t)a*4+1];
        float x2 = boxes[(size_t)a*4+2], y2 = boxes[(size_t)a*4+3];
        bx1[i] = x1; by1[i] = y1; bx2[i] = x2; by2[i] = y2;
        bar[i] = fmaxf(x2 - x1, 0.0f) * fmaxf(y2 - y1, 0.0f);
    }
    __syncthreads();

    for (int i = tid; i < T; i += 256) {
        u64 m[NWORDS] = {0,0,0,0,0};
        float x1 = bx1[i], y1 = by1[i], x2 = bx2[i], y2 = by2[i], ai = bar[i];
        for (int j = i + 1; j < T; ++j) {
            float iw = fmaxf(fminf(x2, bx2[j]) - fmaxf(x1, bx1[j]), 0.0f);
            float ih = fmaxf(fminf(y2, by2[j]) - fmaxf(y1, by1[j]), 0.0f);
            float inter = iw * ih;
            float uni = ((ai + bar[j]) - inter) + 1e-8f;
            if (inter / uni > 0.5f) m[j >> 6] |= 1ull << (j & 63);
        }
        for (int k2 = 0; k2 < NWORDS; ++k2) iomask[i][k2] = m[k2];
    }
    __syncthreads();

    if (tid == 0) {
        u64 sup[NWORDS] = {0,0,0,0,0};
        u64 kp [NWORDS] = {0,0,0,0,0};
        for (int i = 0; i < T; ++i) {
            if (!((sup[i >> 6] >> (i & 63)) & 1ull)) {
                kp[i >> 6] |= 1ull << (i & 63);
                for (int k2 = 0; k2 < NWORDS; ++k2) sup[k2] |= iomask[i][k2];
            }
        }
        for (int k2 = 0; k2 < NWORDS; ++k2) keepm[k2] = kp[k2];
    }
    __syncthreads();

    for (int i = tid; i < T; i += 256) {
        if ((keepm[i >> 6] >> (i & 63)) & 1ull) {
            u64 key = cand[i];
            u32 a = ~(u32)(key & 0xFFFFFFFFull);
            u32 sbits = (u32)(key >> 32);
            u64 outk = ((u64)sbits << 32) | (u32)(255 - c);
            atomicMax(&akey[a], outk);
        }
    }
}

extern "C" void kernel_launch(void* const* d_in, const int* in_sizes, int n_in,
                              void* d_out, int out_size, void* d_ws, size_t ws_size,
                              hipStream_t stream) {
    const float* cls = (const float*)d_in[0];
    const float* reg = (const float*)d_in[1];
    const float* anc = (const float*)d_in[2];
    const int*   ph  = (const int*)d_in[3];
    const int*   pw  = (const int*)d_in[4];

    int A = in_sizes[2] / 4;
    int C = in_sizes[0] / A;

    float* out       = (float*)d_out;
    float* out_boxes = out + (size_t)2 * A;

    // workspace layout: akey | ghist | segcand | segcnt | clsT16
    size_t akey_bytes = (size_t)A * sizeof(u64);
    size_t off_gh     = (akey_bytes + 255) & ~(size_t)255;
    size_t gh_bytes   = (size_t)C * HBINS * sizeof(u32);
    size_t off_cand   = (off_gh + gh_bytes + 255) & ~(size_t)255;
    size_t cand_bytes = (size_t)C * NSEG * SEGCAP * sizeof(u64);
    size_t off_cnt    = (off_cand + cand_bytes + 255) & ~(size_t)255;
    size_t cnt_bytes  = (size_t)C * NSEG * sizeof(u32);
    size_t off_t16    = (off_cnt + cnt_bytes + 255) & ~(size_t)255;
    size_t t16_bytes  = (size_t)A * C * sizeof(unsigned short);
    size_t need       = off_t16 + t16_bytes;

    u64* akey = (u64*)d_ws;

    decode_kernel<<<(A + 255) / 256, 256, 0, stream>>>(anc, reg, ph, pw, out_boxes, akey, A);

    bool fastpath = (C == 80) && (A < (1 << 20)) && (ws_size >= need);
    if (fastpath) {
        u32* ghist   = (u32*)((char*)d_ws + off_gh);
        u64* segcand = (u64*)((char*)d_ws + off_cand);
        u32* segcnt  = (u32*)((char*)d_ws + off_cnt);
        unsigned short* clsT16 = (unsigned short*)((char*)d_ws + off_t16);
        int segsz = (((A + NSEG - 1) / NSEG) + 7) & ~7;

        hipMemsetAsync(ghist, 0, gh_bytes, stream);
        transpose_bin_kernel<<<(A + TTA - 1) / TTA, 256, 0, stream>>>(cls, clsT16, A);
        seg_select_kernel<<<C * NSEG, 256, 0, stream>>>(clsT16, cls, ghist, segcand, segcnt, A, C, segsz);
        class_nms_kernel<<<C, 512, 0, stream>>>(ghist, segcand, segcnt, out_boxes, akey, A, C);
    } else {
        fb_topk_nms_kernel<<<C, 256, 0, stream>>>(cls, out_boxes, akey, A, C);
    }

    finalize_kernel<<<(A + 255) / 256, 256, 0, stream>>>(akey, out, A);
}

// Round 5
// 148.354 us; speedup vs baseline: 1.4882x; 1.4882x over previous
//
#include <hip/hip_runtime.h>
#include <cstdint>

typedef unsigned long long u64;
typedef unsigned int u32;

#define CLS_T    0.05f
#define TOPK     300
#define NWORDS   5          // ceil(300/64)
#define HBINS    2560
#define KEY_BASE 0x3D000000u
#define NSEG     8
#define SEGCAP   512
#define CCAP     1024
#define TTA      128        // anchors per transpose tile

// score -> coarse bin (0 = below threshold)
__device__ inline unsigned short score_bin(float s) {
    if (!(s > CLS_T)) return 0;
    u32 k = __float_as_uint(s) - KEY_BASE;
    u32 b = k >> 14;
    if (b > (HBINS - 1)) b = HBINS - 1;
    return (unsigned short)b;
}
__device__ inline u32 bin_of_bits(u32 bits) {
    u32 b = (bits - KEY_BASE) >> 14;
    if (b > (HBINS - 1)) b = HBINS - 1;
    return b;
}

// compare-exchange for register bitonic: keep max if (lo==up), else min
__device__ inline void cex(u64& v, u64 p, bool lo, bool up) {
    u64 mx = v > p ? v : p;
    u64 mn = v > p ? p : v;
    v = (lo == up) ? mx : mn;
}
__device__ inline void sstep(u64& a0, u64& a1, u32 tid, u32 kk, u32 j) {
    u64 p0 = __shfl_xor((unsigned long long)a0, (int)j, 64);
    u64 p1 = __shfl_xor((unsigned long long)a1, (int)j, 64);
    bool lo = ((tid & j) == 0);
    cex(a0, p0, lo, ((tid & kk) == 0));
    cex(a1, p1, lo, (((tid + 512u) & kk) == 0));
}
__device__ inline void lstep(u64* cand, u64& a0, u64& a1, u32 tid, u32 kk, u32 j) {
    __syncthreads();                 // protect earlier reads
    cand[tid] = a0; cand[tid + 512] = a1;
    __syncthreads();
    u64 p0 = cand[tid ^ j], p1 = cand[(tid ^ j) + 512];
    bool lo = ((tid & j) == 0);
    cex(a0, p0, lo, ((tid & kk) == 0));
    cex(a1, p1, lo, (((tid + 512u) & kk) == 0));
}

// ---------------- decode boxes (+clip) + zero akey ----------------
__global__ void decode_kernel(const float* __restrict__ anc,
                              const float* __restrict__ reg,
                              const int* __restrict__ ph,
                              const int* __restrict__ pw,
                              float* __restrict__ boxes,
                              u64* __restrict__ akey, int A)
{
    int a = blockIdx.x * blockDim.x + threadIdx.x;
    if (a >= A) return;
    akey[a] = 0;
    float x1 = anc[a*4+0], y1 = anc[a*4+1], x2 = anc[a*4+2], y2 = anc[a*4+3];
    float w = x2 - x1, h = y2 - y1;
    float cx = x1 + 0.5f*w, cy = y1 + 0.5f*h;
    float r0 = reg[a*4+0]*0.1f, r1 = reg[a*4+1]*0.1f;
    float r2 = reg[a*4+2]*0.2f, r3 = reg[a*4+3]*0.2f;
    float pcx = cx + r0*w, pcy = cy + r1*h;
    float pw_ = expf(r2)*w, ph_ = expf(r3)*h;
    float W = (float)(*pw), H = (float)(*ph);
    boxes[a*4+0] = fmaxf(pcx - 0.5f*pw_, 0.0f);
    boxes[a*4+1] = fmaxf(pcy - 0.5f*ph_, 0.0f);
    boxes[a*4+2] = fminf(pcx + 0.5f*pw_, W);
    boxes[a*4+3] = fminf(pcy + 0.5f*ph_, H);
}

// ---------------- transpose cls[A][80] -> bin16[80][A] ----------------
__global__ __launch_bounds__(256) void transpose_bin_kernel(
    const float* __restrict__ in, unsigned short* __restrict__ out, int A)
{
    const int C = 80;
    __shared__ unsigned short tile[TTA][81];
    int a0 = blockIdx.x * TTA;
    int rows = A - a0; if (rows > TTA) rows = TTA;

    if (rows == TTA) {
        const float4* in4 = (const float4*)(in + (size_t)a0 * C);
        for (int w = threadIdx.x; w < TTA * C / 4; w += 256) {
            float4 v = in4[w];
            int l = w * 4; int r = l / C; int cc = l - r * C;
            tile[r][cc+0] = score_bin(v.x);
            tile[r][cc+1] = score_bin(v.y);
            tile[r][cc+2] = score_bin(v.z);
            tile[r][cc+3] = score_bin(v.w);
        }
        __syncthreads();
        for (int m = threadIdx.x; m < C * (TTA/2); m += 256) {
            int cc = m >> 6;
            int r2 = (m & (TTA/2 - 1)) << 1;
            u32 wv = (u32)tile[r2][cc] | ((u32)tile[r2+1][cc] << 16);
            *(u32*)(out + (size_t)cc * A + a0 + r2) = wv;
        }
    } else {
        for (int l = threadIdx.x; l < rows * C; l += 256) {
            int r = l / C; int cc = l - r * C;
            tile[r][cc] = score_bin(in[(size_t)(a0 + r) * C + cc]);
        }
        __syncthreads();
        for (int m = threadIdx.x; m < C * rows; m += 256) {
            int cc = m / rows; int r = m - cc * rows;
            out[(size_t)cc * A + a0 + r] = tile[r][cc];
        }
    }
}

// ---------------- per-(class,segment) selection + global hist merge ----------------
__global__ __launch_bounds__(256) void seg_select_kernel(
    const unsigned short* __restrict__ clsT16,
    const float* __restrict__ cls,     // [A][C] exact scores for gather
    u32* __restrict__ ghist,           // [C][HBINS], pre-zeroed
    u64* __restrict__ segcand, u32* __restrict__ segcnt,
    int A, int C, int segsz)
{
    const int blk = blockIdx.x;
    const int c = blk >> 3, seg = blk & 7;
    const int tid = threadIdx.x;
    int a0 = seg * segsz;
    int a1 = a0 + segsz; if (a1 > A) a1 = A;

    __shared__ u32 hist[HBINS];
    __shared__ u32 s_sel, s_cnt;

    if (a0 >= A) { if (tid == 0) segcnt[blk] = 0; return; }

    for (int i = tid; i < HBINS; i += 256) hist[i] = 0;
    if (tid == 0) { s_sel = 0; s_cnt = 0; }
    __syncthreads();

    const unsigned short* row = clsT16 + (size_t)c * A;
    const int n = a1 - a0;
    const int n8 = n >> 3;
    const uint4* p4 = (const uint4*)(row + a0);
    for (int i = tid; i < n8; i += 256) {
        uint4 v = p4[i];
        u32 ws[4] = {v.x, v.y, v.z, v.w};
        #pragma unroll
        for (int q = 0; q < 4; ++q) {
            u32 e0 = ws[q] & 0xFFFFu, e1 = ws[q] >> 16;
            if (e0) atomicAdd(&hist[e0], 1u);
            if (e1) atomicAdd(&hist[e1], 1u);
        }
    }
    for (int a = a0 + (n8 << 3) + tid; a < a1; a += 256) {
        u32 e = row[a];
        if (e) atomicAdd(&hist[e], 1u);
    }
    __syncthreads();

    // merge into global per-class histogram (all threads)
    for (int i = tid; i < HBINS; i += 256) {
        u32 h = hist[i];
        if (h) atomicAdd(&ghist[(size_t)c * HBINS + i], h);
    }
    // single-wave suffix scan (wave 0, no block barriers)
    if (tid < 64) {
        int base = HBINS - (tid + 1) * 40;
        u32 csum = 0;
        for (int q = 0; q < 40; ++q) csum += hist[base + q];
        u32 pref = csum;
        for (int d = 1; d < 64; d <<= 1) {
            u32 v = __shfl_up(pref, d);
            if (tid >= d) pref += v;
        }
        if (pref >= TOPK && (pref - csum) < TOPK) {
            u32 run = pref - csum;
            for (int q = 39; q >= 0; --q) {
                run += hist[base + q];
                if (run >= TOPK) { s_sel = (u32)(base + q); break; }
            }
        }
    }
    __syncthreads();
    u32 sel = s_sel < 1 ? 1 : s_sel;

    // collect: rescan segment (L2-resident), gather exact bits
    u64* outc = segcand + (size_t)blk * SEGCAP;
    for (int a = a0 + tid; a < a1; a += 256) {
        u32 e = row[a];
        if (e >= sel) {
            u32 bits = __float_as_uint(cls[(size_t)a * C + c]);
            u32 p = atomicAdd(&s_cnt, 1u);
            if (p < SEGCAP) outc[p] = ((u64)bits << 32) | (u32)(~(u32)a);
        }
    }
    __syncthreads();
    if (tid == 0) segcnt[blk] = s_cnt < SEGCAP ? s_cnt : SEGCAP;
}

// ---------------- per-class collect: threshold, filtered load, register sort ----------------
__global__ __launch_bounds__(512) void class_collect_kernel(
    const u32* __restrict__ ghist,
    const u64* __restrict__ segcand, const u32* __restrict__ segcnt,
    u64* __restrict__ topkeys, u32* __restrict__ topcnt, int C)
{
    const int c = blockIdx.x;
    const u32 tid = threadIdx.x;
    const int lane = tid & 63;

    __shared__ u64 cand[CCAP];
    __shared__ u32 s_sel, s_cnt;

    if (tid == 0) { s_sel = 0; s_cnt = 0; }
    __syncthreads();

    // threshold via single-wave suffix scan over ghist[c]
    if (tid < 64) {
        const u32* gh = ghist + (size_t)c * HBINS;
        int base = HBINS - ((int)tid + 1) * 40;
        u32 csum = 0;
        for (int q = 0; q < 40; ++q) csum += gh[base + q];
        u32 pref = csum;
        for (int d = 1; d < 64; d <<= 1) {
            u32 v = __shfl_up(pref, d);
            if (lane >= d) pref += v;
        }
        if (pref >= TOPK && (pref - csum) < TOPK) {
            u32 run = pref - csum;
            for (int q = 39; q >= 0; --q) {
                run += gh[base + q];
                if (run >= TOPK) { s_sel = (u32)(base + q); break; }
            }
        }
    }
    __syncthreads();
    const u32 thr = s_sel < 1 ? 1 : s_sel;

    // filtered load + wave-aggregated compaction
    for (int s2 = 0; s2 < NSEG; ++s2) {
        int cnt_s = (int)segcnt[c * NSEG + s2];
        const u64* src = segcand + (size_t)(c * NSEG + s2) * SEGCAP;
        for (int i = tid; i < (u32)cnt_s; i += 512) {
            u64 e = src[i];
            bool take = bin_of_bits((u32)(e >> 32)) >= thr;
            u64 m = __ballot(take);
            int nW = __popcll(m);
            if (nW) {
                int ldr = __ffsll((unsigned long long)m) - 1;
                u32 base2 = 0;
                if (lane == ldr) base2 = atomicAdd(&s_cnt, (u32)nW);
                base2 = __shfl(base2, ldr);
                if (take) {
                    u32 p = base2 + (u32)__popcll(m & ((1ull << lane) - 1ull));
                    if (p < CCAP) cand[p] = e;
                }
            }
        }
    }
    __syncthreads();
    const u32 cnt = s_cnt < CCAP ? s_cnt : CCAP;
    for (u32 i = cnt + tid; i < CCAP; i += 512) cand[i] = 0;
    __syncthreads();

    // ---- register bitonic sort of 1024 (2 elems/thread), descending ----
    u64 a0 = cand[tid], a1 = cand[tid + 512];
    for (u32 kk = 2; kk <= 64; kk <<= 1)
        for (u32 j = kk >> 1; j >= 1; j >>= 1)
            sstep(a0, a1, tid, kk, j);
    lstep(cand, a0, a1, tid, 128u, 64u);
    for (u32 j = 32; j >= 1; j >>= 1) sstep(a0, a1, tid, 128u, j);
    lstep(cand, a0, a1, tid, 256u, 128u);
    lstep(cand, a0, a1, tid, 256u, 64u);
    for (u32 j = 32; j >= 1; j >>= 1) sstep(a0, a1, tid, 256u, j);
    lstep(cand, a0, a1, tid, 512u, 256u);
    lstep(cand, a0, a1, tid, 512u, 128u);
    lstep(cand, a0, a1, tid, 512u, 64u);
    for (u32 j = 32; j >= 1; j >>= 1) sstep(a0, a1, tid, 512u, j);
    {   // kk=1024, j=512: in-thread exchange
        u64 mx = a0 > a1 ? a0 : a1, mn = a0 > a1 ? a1 : a0;
        a0 = mx; a1 = mn;          // up = ((tid&1024)==0) = true
    }
    lstep(cand, a0, a1, tid, 1024u, 256u);
    lstep(cand, a0, a1, tid, 1024u, 128u);
    lstep(cand, a0, a1, tid, 1024u, 64u);
    for (u32 j = 32; j >= 1; j >>= 1) sstep(a0, a1, tid, 1024u, j);

    // thread tid holds sorted element tid in a0
    if (tid < TOPK) topkeys[(size_t)c * TOPK + tid] = a0;
    if (tid == 0) topcnt[c] = cnt < TOPK ? cnt : TOPK;
}

// ---------------- per-class NMS: colmask in regs + fixpoint greedy ----------------
__global__ __launch_bounds__(320) void class_nms2_kernel(
    const u64* __restrict__ topkeys, const u32* __restrict__ topcnt,
    const float* __restrict__ boxes, u64* __restrict__ akey, int C)
{
    const int c = blockIdx.x;
    const int tid = threadIdx.x;
    const int lane = tid & 63;
    const int wv = tid >> 6;

    __shared__ float bx1[TOPK], by1[TOPK], bx2[TOPK], by2[TOPK], bar[TOPK];
    __shared__ u64 s_alive[NWORDS], s_newalive[NWORDS];
    __shared__ u32 s_changed;

    const int T = (int)topcnt[c];

    u64 key = 0; u32 aidx = 0;
    float x1 = 0, y1 = 0, x2 = 0, y2 = 0, ar = 0;
    if (tid < T) {
        key = topkeys[(size_t)c * TOPK + tid];
        aidx = ~(u32)(key & 0xFFFFFFFFull);
        x1 = boxes[(size_t)aidx*4+0]; y1 = boxes[(size_t)aidx*4+1];
        x2 = boxes[(size_t)aidx*4+2]; y2 = boxes[(size_t)aidx*4+3];
        ar = fmaxf(x2 - x1, 0.0f) * fmaxf(y2 - y1, 0.0f);
        bx1[tid] = x1; by1[tid] = y1; bx2[tid] = x2; by2[tid] = y2; bar[tid] = ar;
    }
    if (tid < NWORDS) {
        int rem = T - tid * 64;
        s_alive[tid] = rem >= 64 ? ~0ull : (rem > 0 ? ((1ull << rem) - 1ull) : 0ull);
    }
    if (tid == 0) s_changed = 0;
    __syncthreads();

    // colmask: which i<tid suppress me (IoU>0.5), in registers
    u64 cm[NWORDS] = {0,0,0,0,0};
    if (tid < T) {
        for (int i = 0; i < tid; ++i) {
            float iw = fmaxf(fminf(x2, bx2[i]) - fmaxf(x1, bx1[i]), 0.0f);
            float ih = fmaxf(fminf(y2, by2[i]) - fmaxf(y1, by1[i]), 0.0f);
            float inter = iw * ih;
            float uni = ((ar + bar[i]) - inter) + 1e-8f;
            float q = inter - 0.5f * uni;           // 0.5*uni exact; sign(q) exact
            bool sup;
            if (fabsf(q) > 1e-5f * uni) sup = (q > 0.0f);
            else sup = (inter / uni > 0.5f);        // rare boundary: exact semantics
            if (sup) cm[i >> 6] |= 1ull << (i & 63);
        }
    }

    // synchronous fixpoint: alive(j) = !exists i<j alive & sup(i,j); == greedy keep set
    for (int round = 0; round < TOPK; ++round) {
        u64 al[NWORDS];
        #pragma unroll
        for (int k2 = 0; k2 < NWORDS; ++k2) al[k2] = s_alive[k2];
        bool alive_t = false;
        if (tid < T) {
            u64 any = 0;
            #pragma unroll
            for (int k2 = 0; k2 < NWORDS; ++k2) any |= (al[k2] & cm[k2]);
            alive_t = (any == 0);
        }
        u64 w = __ballot(alive_t);
        if (lane == 0) {
            s_newalive[wv] = w;
            if (w != al[wv]) s_changed = 1;
        }
        __syncthreads();
        u32 ch = s_changed;
        __syncthreads();
        if (!ch) break;
        if (tid < NWORDS) s_alive[tid] = s_newalive[tid];
        if (tid == 0) s_changed = 0;
        __syncthreads();
    }

    if (tid < T) {
        if ((s_alive[tid >> 6] >> (tid & 63)) & 1ull) {
            u32 sbits = (u32)(key >> 32);
            u64 outk = ((u64)sbits << 32) | (u32)(255 - c);
            atomicMax(&akey[aidx], outk);
        }
    }
}

// ---------------- finalize ----------------
__global__ void finalize_kernel(const u64* __restrict__ akey,
                                float* __restrict__ out, int A)
{
    int a = blockIdx.x * blockDim.x + threadIdx.x;
    if (a >= A) return;
    float* scores = out;
    float* labels = out + A;
    float* boxes  = out + (size_t)2 * A;
    u64 k = akey[a];
    if (k) {
        scores[a] = __uint_as_float((u32)(k >> 32));
        labels[a] = (float)(int)(255u - (u32)(k & 0xFFFFFFFFull));
    } else {
        scores[a] = 0.0f;
        labels[a] = -1.0f;
        boxes[(size_t)a*4+0] = 0.0f;
        boxes[(size_t)a*4+1] = 0.0f;
        boxes[(size_t)a*4+2] = 0.0f;
        boxes[(size_t)a*4+3] = 0.0f;
    }
}

// ---------------- fallback: round-1 proven kernel ----------------
#define FB_CAP 1024
__global__ __launch_bounds__(256) void fb_topk_nms_kernel(
    const float* __restrict__ cls,
    const float* __restrict__ boxes,
    u64* __restrict__ akey,
    int A, int C)
{
    const int c   = blockIdx.x;
    const int tid = threadIdx.x;

    __shared__ u32 hist[HBINS];
    __shared__ u64 cand[FB_CAP];
    __shared__ float bx1[TOPK], by1[TOPK], bx2[TOPK], by2[TOPK], bar[TOPK];
    __shared__ u64 iomask[TOPK][NWORDS];
    __shared__ u64 keepm[NWORDS];
    __shared__ u32 s_sel1, s_sel2, s_rem, s_cnt;

    for (int i = tid; i < HBINS; i += 256) hist[i] = 0;
    __syncthreads();
    for (int a = tid; a < A; a += 256) {
        float s = cls[(size_t)a * C + c];
        if (s > CLS_T) {
            u32 k = __float_as_uint(s) - KEY_BASE;
            u32 b = k >> 14; if (b >= HBINS) b = HBINS - 1;
            atomicAdd(&hist[b], 1u);
        }
    }
    __syncthreads();
    if (tid == 0) {
        u32 cum = 0; int sel = 0;
        for (int d = HBINS - 1; d >= 0; --d) {
            u32 nc = cum + hist[d];
            if (nc >= TOPK) { sel = d; break; }
            cum = nc;
        }
        s_sel1 = (u32)sel; s_rem = TOPK - cum;
    }
    __syncthreads();
    const u32 sel1 = s_sel1;

    for (int i = tid; i < 256; i += 256) hist[i] = 0;
    __syncthreads();
    for (int a = tid; a < A; a += 256) {
        float s = cls[(size_t)a * C + c];
        if (s > CLS_T) {
            u32 k = __float_as_uint(s) - KEY_BASE;
            u32 b = k >> 14; if (b >= HBINS) b = HBINS - 1;
            if (b == sel1) atomicAdd(&hist[(k >> 6) & 0xFF], 1u);
        }
    }
    __syncthreads();
    if (tid == 0) {
        u32 rem = s_rem, cum = 0; int sel = 0;
        for (int d = 255; d >= 0; --d) {
            u32 nc = cum + hist[d];
            if (nc >= rem) { sel = d; break; }
            cum = nc;
        }
        s_sel2 = (u32)sel; s_cnt = 0;
    }
    __syncthreads();
    const u32 thresh = (sel1 << 14) | (s_sel2 << 6);

    for (int a = tid; a < A; a += 256) {
        float s = cls[(size_t)a * C + c];
        if (s > CLS_T) {
            u32 bits = __float_as_uint(s);
            u32 k = bits - KEY_BASE;
            if (k >= thresh) {
                u32 pos = atomicAdd(&s_cnt, 1u);
                if (pos < FB_CAP) cand[pos] = ((u64)bits << 32) | (u32)(~(u32)a);
            }
        }
    }
    __syncthreads();
    const u32 total = s_cnt < FB_CAP ? s_cnt : FB_CAP;
    for (int i = tid; i < FB_CAP; i += 256)
        if (i >= (int)total) cand[i] = 0;
    __syncthreads();

    for (u32 kk = 2; kk <= FB_CAP; kk <<= 1) {
        for (u32 j = kk >> 1; j > 0; j >>= 1) {
            for (u32 i = tid; i < FB_CAP; i += 256) {
                u32 l = i ^ j;
                if (l > i) {
                    u64 av = cand[i], bv = cand[l];
                    bool up = ((i & kk) == 0);
                    if ((up && av < bv) || (!up && av > bv)) { cand[i] = bv; cand[l] = av; }
                }
            }
            __syncthreads();
        }
    }
    const int T = (int)(total < TOPK ? total : TOPK);

    for (int i = tid; i < T; i += 256) {
        u32 a = ~(u32)(cand[i] & 0xFFFFFFFFull);
        float x1 = boxes[(size_t)a*4+0], y1 = boxes[(size_t)a*4+1];
        float x2 = boxes[(size_t)a*4+2], y2 = boxes[(size_t)a*4+3];
        bx1[i] = x1; by1[i] = y1; bx2[i] = x2; by2[i] = y2;
        bar[i] = fmaxf(x2 - x1, 0.0f) * fmaxf(y2 - y1, 0.0f);
    }
    __syncthreads();

    for (int i = tid; i < T; i += 256) {
        u64 m[NWORDS] = {0,0,0,0,0};
        float x1 = bx1[i], y1 = by1[i], x2 = bx2[i], y2 = by2[i], ai = bar[i];
        for (int j = i + 1; j < T; ++j) {
            float iw = fmaxf(fminf(x2, bx2[j]) - fmaxf(x1, bx1[j]), 0.0f);
            float ih = fmaxf(fminf(y2, by2[j]) - fmaxf(y1, by1[j]), 0.0f);
            float inter = iw * ih;
            float uni = ((ai + bar[j]) - inter) + 1e-8f;
            if (inter / uni > 0.5f) m[j >> 6] |= 1ull << (j & 63);
        }
        for (int k2 = 0; k2 < NWORDS; ++k2) iomask[i][k2] = m[k2];
    }
    __syncthreads();

    if (tid == 0) {
        u64 sup[NWORDS] = {0,0,0,0,0};
        u64 kp [NWORDS] = {0,0,0,0,0};
        for (int i = 0; i < T; ++i) {
            if (!((sup[i >> 6] >> (i & 63)) & 1ull)) {
                kp[i >> 6] |= 1ull << (i & 63);
                for (int k2 = 0; k2 < NWORDS; ++k2) sup[k2] |= iomask[i][k2];
            }
        }
        for (int k2 = 0; k2 < NWORDS; ++k2) keepm[k2] = kp[k2];
    }
    __syncthreads();

    for (int i = tid; i < T; i += 256) {
        if ((keepm[i >> 6] >> (i & 63)) & 1ull) {
            u64 key = cand[i];
            u32 a = ~(u32)(key & 0xFFFFFFFFull);
            u32 sbits = (u32)(key >> 32);
            u64 outk = ((u64)sbits << 32) | (u32)(255 - c);
            atomicMax(&akey[a], outk);
        }
    }
}

extern "C" void kernel_launch(void* const* d_in, const int* in_sizes, int n_in,
                              void* d_out, int out_size, void* d_ws, size_t ws_size,
                              hipStream_t stream) {
    const float* cls = (const float*)d_in[0];
    const float* reg = (const float*)d_in[1];
    const float* anc = (const float*)d_in[2];
    const int*   ph  = (const int*)d_in[3];
    const int*   pw  = (const int*)d_in[4];

    int A = in_sizes[2] / 4;
    int C = in_sizes[0] / A;

    float* out       = (float*)d_out;
    float* out_boxes = out + (size_t)2 * A;

    // workspace layout: akey | ghist | segcand | segcnt | topkeys | topcnt | clsT16
    size_t akey_bytes = (size_t)A * sizeof(u64);
    size_t off_gh     = (akey_bytes + 255) & ~(size_t)255;
    size_t gh_bytes   = (size_t)C * HBINS * sizeof(u32);
    size_t off_cand   = (off_gh + gh_bytes + 255) & ~(size_t)255;
    size_t cand_bytes = (size_t)C * NSEG * SEGCAP * sizeof(u64);
    size_t off_cnt    = (off_cand + cand_bytes + 255) & ~(size_t)255;
    size_t cnt_bytes  = (size_t)C * NSEG * sizeof(u32);
    size_t off_tk     = (off_cnt + cnt_bytes + 255) & ~(size_t)255;
    size_t tk_bytes   = (size_t)C * TOPK * sizeof(u64);
    size_t off_tc     = (off_tk + tk_bytes + 255) & ~(size_t)255;
    size_t tc_bytes   = (size_t)C * sizeof(u32);
    size_t off_t16    = (off_tc + tc_bytes + 255) & ~(size_t)255;
    size_t t16_bytes  = (size_t)A * C * sizeof(unsigned short);
    size_t need       = off_t16 + t16_bytes;

    u64* akey = (u64*)d_ws;

    decode_kernel<<<(A + 255) / 256, 256, 0, stream>>>(anc, reg, ph, pw, out_boxes, akey, A);

    bool fastpath = (C == 80) && (A < (1 << 20)) && (ws_size >= need);
    if (fastpath) {
        u32* ghist   = (u32*)((char*)d_ws + off_gh);
        u64* segcand = (u64*)((char*)d_ws + off_cand);
        u32* segcnt  = (u32*)((char*)d_ws + off_cnt);
        u64* topkeys = (u64*)((char*)d_ws + off_tk);
        u32* topcnt  = (u32*)((char*)d_ws + off_tc);
        unsigned short* clsT16 = (unsigned short*)((char*)d_ws + off_t16);
        int segsz = (((A + NSEG - 1) / NSEG) + 7) & ~7;

        hipMemsetAsync(ghist, 0, gh_bytes, stream);
        transpose_bin_kernel<<<(A + TTA - 1) / TTA, 256, 0, stream>>>(cls, clsT16, A);
        seg_select_kernel<<<C * NSEG, 256, 0, stream>>>(clsT16, cls, ghist, segcand, segcnt, A, C, segsz);
        class_collect_kernel<<<C, 512, 0, stream>>>(ghist, segcand, segcnt, topkeys, topcnt, C);
        class_nms2_kernel<<<C, 320, 0, stream>>>(topkeys, topcnt, out_boxes, akey, C);
    } else {
        fb_topk_nms_kernel<<<C, 256, 0, stream>>>(cls, out_boxes, akey, A, C);
    }

    finalize_kernel<<<(A + 255) / 256, 256, 0, stream>>>(akey, out, A);
}